// Round 3
// baseline (1091.296 us; speedup 1.0000x reference)
//
#include <hip/hip_runtime.h>

#define T_LEN 2048
#define DH 256
#define NCHUNK (T_LEN / 16)

typedef short short8 __attribute__((ext_vector_type(8)));
typedef float f32x4 __attribute__((ext_vector_type(4)));

__device__ __forceinline__ unsigned short f2bf(float f) {
  unsigned u = __builtin_bit_cast(unsigned, f);
  u += 0x7fffu + ((u >> 16) & 1u);   // round-to-nearest-even
  return (unsigned short)(u >> 16);
}

// Raw WG barrier: flush this wave's LDS ops, barrier, fence the scheduler.
// Deliberately does NOT drain vmcnt — prefetch loads / h stores stay in
// flight across steps (no cross-wave hazard goes through global memory).
#define WG_BARRIER() do {                                   \
  __builtin_amdgcn_sched_barrier(0);                        \
  asm volatile("s_waitcnt lgkmcnt(0)" ::: "memory");        \
  __builtin_amdgcn_s_barrier();                             \
  __builtin_amdgcn_sched_barrier(0);                        \
} while (0)

// ---------------------------------------------------------------------------
// Phase 1: out = x @ W_in + b_in + b_h   (b_h folded in so the scan epilogue
// is shorter). Grid 512 x 256 thr; wave w owns cols [64w, 64w+64).
// MFMA 16x16x32 bf16. A[m][k]: m=lane&15, k=(lane>>4)*8+j; B same k, c=lane&15;
// D: c=lane&15, m=(lane>>4)*4+r.
// ---------------------------------------------------------------------------
__global__ __launch_bounds__(256, 1) void xproj_gemm(
    const float* __restrict__ x, const float* __restrict__ W_in,
    const float* __restrict__ b_in, const float* __restrict__ b_h,
    float* __restrict__ out) {
  const int tid  = threadIdx.x;
  const int lane = tid & 63;
  const int w    = tid >> 6;
  const int l15  = lane & 15;
  const int lg   = lane >> 4;
  const int koff = lg * 8;
  const int m0   = blockIdx.x * 128;

  short8 Bf[4][8];
#pragma unroll
  for (int n = 0; n < 4; ++n) {
    const int c = 64 * w + 16 * n + l15;
#pragma unroll
    for (int kk = 0; kk < 8; ++kk) {
      short8 bf;
#pragma unroll
      for (int j = 0; j < 8; ++j)
        bf[j] = (short)f2bf(W_in[(32 * kk + koff + j) * DH + c]);
      Bf[n][kk] = bf;
    }
  }
  float bin[4];
#pragma unroll
  for (int n = 0; n < 4; ++n) {
    const int c = 64 * w + 16 * n + l15;
    bin[n] = b_in[c] + b_h[c];
  }

  for (int slab = 0; slab < 8; ++slab) {
    const float* xr = x + (size_t)(m0 + slab * 16 + l15) * DH;
    short8 A[8];
#pragma unroll
    for (int kk = 0; kk < 8; ++kk) {
      f32x4 v0 = *(const f32x4*)(xr + 32 * kk + koff);
      f32x4 v1 = *(const f32x4*)(xr + 32 * kk + koff + 4);
      short8 a;
      a[0] = f2bf(v0[0]); a[1] = f2bf(v0[1]); a[2] = f2bf(v0[2]); a[3] = f2bf(v0[3]);
      a[4] = f2bf(v1[0]); a[5] = f2bf(v1[1]); a[6] = f2bf(v1[2]); a[7] = f2bf(v1[3]);
      A[kk] = a;
    }
    f32x4 acc[4];
#pragma unroll
    for (int n = 0; n < 4; ++n) acc[n] = (f32x4){0.f, 0.f, 0.f, 0.f};
#pragma unroll
    for (int kk = 0; kk < 8; ++kk)
#pragma unroll
      for (int n = 0; n < 4; ++n)
        acc[n] = __builtin_amdgcn_mfma_f32_16x16x32_bf16(A[kk], Bf[n][kk], acc[n], 0, 0, 0);
#pragma unroll
    for (int n = 0; n < 4; ++n) {
      const int c = 64 * w + 16 * n + l15;
#pragma unroll
      for (int r = 0; r < 4; ++r)
        out[(size_t)(m0 + slab * 16 + lg * 4 + r) * DH + c] = acc[n][r] + bin[n];
    }
  }
}

// ---------------------------------------------------------------------------
// Phase 2: serial scan. Grid 32 (one WG per batch) x 512 thr (8 waves).
// Wave w owns cols [32w, 32w+32) -> Bf[2][8] = 64 VGPRs/lane.
// h: bf16 in double-buffered LDS row. Steady-state step:
//   barrier-release -> 8 exec-masked ds_read_b128 (A-frag) -> 16 MFMA as
//   4 independent depth-2 chains per col-tile -> 3 adds + relu -> direct
//   global store of h_t (no wait needed) + 2 ds_write_b16 -> barrier.
// x_proj consumed from LDS chunks prefetched one chunk ahead into regs;
// x_proj+b_in+b_h folded into accumulator chain 0 element 0.
// ---------------------------------------------------------------------------
__global__ __launch_bounds__(512, 2) void rnn_scan(
    const float* __restrict__ h0, const float* __restrict__ W_h,
    float* __restrict__ out) {
  __shared__ __align__(16) unsigned short hbuf[2][DH];
  __shared__ __align__(16) float xpb[2][16 * DH];

  const int tid  = threadIdx.x;
  const int lane = tid & 63;
  const int w    = tid >> 6;         // 0..7
  const int l15  = lane & 15;
  const int lg   = lane >> 4;
  const int koff = lg * 8;
  const int b    = blockIdx.x;
  float* outb = out + (size_t)b * T_LEN * DH;

  // Issue chunk-0 x_proj loads first so they fly under the W_h fragment load.
  f32x4 st[2];
#pragma unroll
  for (int i = 0; i < 2; ++i)
    st[i] = *(const f32x4*)(outb + i * 2048 + tid * 4);

  // W_h bf16 fragments: wave w owns cols [32w, 32w+32) as 2 16-col tiles.
  short8 Bf[2][8];
#pragma unroll
  for (int n = 0; n < 2; ++n) {
    const int c = 32 * w + 16 * n + l15;
#pragma unroll
    for (int kk = 0; kk < 8; ++kk) {
      short8 bf;
#pragma unroll
      for (int j = 0; j < 8; ++j)
        bf[j] = (short)f2bf(W_h[(32 * kk + koff + j) * DH + c]);
      Bf[n][kk] = bf;
    }
  }

  if (tid < DH) hbuf[0][tid] = f2bf(h0[b * DH + tid]);
#pragma unroll
  for (int i = 0; i < 2; ++i)
    *(f32x4*)(&xpb[0][i * 2048 + tid * 4]) = st[i];
#pragma unroll
  for (int i = 0; i < 2; ++i)
    st[i] = *(const f32x4*)(outb + 4096 + i * 2048 + tid * 4);
  __syncthreads();

  // A fragments: rows 1..15 are zeros, set ONCE; only l15==0 lanes overwrite.
  short8 A[8];
#pragma unroll
  for (int kk = 0; kk < 8; ++kk) A[kk] = (short8){0, 0, 0, 0, 0, 0, 0, 0};

  for (int t = 0; t < T_LEN; ++t) {
    const unsigned short* hb = &hbuf[t & 1][0];
    if (l15 == 0) {
#pragma unroll
      for (int kk = 0; kk < 8; ++kk)
        A[kk] = *(const short8*)(hb + 32 * kk + koff);
    }
    // x_proj(+biases) for this step -> goes straight into accumulator init.
    float xb[2];
    if (lane < 16) {
#pragma unroll
      for (int n = 0; n < 2; ++n)
        xb[n] = xpb[(t >> 4) & 1][(t & 15) * DH + 32 * w + 16 * n + lane];
    }

    // 16 MFMAs: 2 col-tiles x 4 independent chains of depth 2.
    // Chain 0 element 0 is seeded with xb (valid for lanes<16; other lanes'
    // accumulators are don't-care rows).
    f32x4 ac[2][4];
#pragma unroll
    for (int n = 0; n < 2; ++n) {
#pragma unroll
      for (int q = 0; q < 4; ++q) ac[n][q] = (f32x4){0.f, 0.f, 0.f, 0.f};
      if (lane < 16) ac[n][0][0] = xb[n];
    }
#pragma unroll
    for (int q = 0; q < 4; ++q)
#pragma unroll
      for (int d = 0; d < 2; ++d)
#pragma unroll
        for (int n = 0; n < 2; ++n)
          ac[n][q] = __builtin_amdgcn_mfma_f32_16x16x32_bf16(A[2 * q + d], Bf[n][2 * q + d], ac[n][q], 0, 0, 0);

    // Valid output row is m=0 -> lanes 0..15, element 0.
    if (lane < 16) {
#pragma unroll
      for (int n = 0; n < 2; ++n) {
        const int c = 32 * w + 16 * n + lane;
        float v = (ac[n][0][0] + ac[n][1][0]) + (ac[n][2][0] + ac[n][3][0]);
        v = fmaxf(v, 0.0f);
        outb[(size_t)t * DH + c] = v;          // direct store, no wait needed
        hbuf[(t + 1) & 1][c] = f2bf(v);
      }
    }

    if ((t & 15) == 15) {
      WG_BARRIER();  // all reads of xp chunk + h writes complete
      const int nc = (t >> 4) + 1;  // chunk to publish (regs -> LDS)
      if (nc < NCHUNK) {
#pragma unroll
        for (int i = 0; i < 2; ++i)
          *(f32x4*)(&xpb[nc & 1][i * 2048 + tid * 4]) = st[i];
        const int pc = nc + 1;      // prefetch following chunk
        if (pc < NCHUNK) {
#pragma unroll
          for (int i = 0; i < 2; ++i)
            st[i] = *(const f32x4*)(outb + (size_t)pc * 4096 + i * 2048 + tid * 4);
        }
      }
      WG_BARRIER();  // xpb chunk visible before next step reads it
    } else {
      WG_BARRIER();  // h_{t+1} visible before next step's A-frag reads
    }
  }
}

extern "C" void kernel_launch(void* const* d_in, const int* in_sizes, int n_in,
                              void* d_out, int out_size, void* d_ws, size_t ws_size,
                              hipStream_t stream) {
  const float* x    = (const float*)d_in[0];
  const float* h0   = (const float*)d_in[1];
  const float* W_in = (const float*)d_in[2];
  const float* b_in = (const float*)d_in[3];
  const float* W_h  = (const float*)d_in[4];
  const float* b_h  = (const float*)d_in[5];
  float* out = (float*)d_out;

  hipLaunchKernelGGL(xproj_gemm, dim3(512), dim3(256), 0, stream, x, W_in, b_in, b_h, out);
  hipLaunchKernelGGL(rnn_scan, dim3(32), dim3(512), 0, stream, h0, W_h, out);
}